// Round 1
// 2005.923 us; speedup vs baseline: 3.1179x; 3.1179x over previous
//
#include <hip/hip_runtime.h>
#include <hip/hip_bf16.h>

#define N_USER 100000
#define N_ITEM 200000
#define N_NODE 300000
#define LATDIM 64
#define E_INTER 4000000
#define E_SOC  2000000

#define NODE_ELEMS (N_NODE * LATDIM)   // 19,200,000
#define USER_ELEMS (N_USER * LATDIM)   // 6,400,000

// ---------------------------------------------------------------------------
// workspace layout (bytes), all offsets 16B-aligned:
//   socA     bf16[USER_ELEMS]        @ 0            12,800,000
//   socB     bf16[USER_ELEMS]        @ 12,800,000   12,800,000
//   fused    bf16[5*NODE_ELEMS]      @ 25,600,000  192,000,000
//   iPairs   u64 [E_INTER]           @ 217,600,000  32,000,000
//   sPairs   u64 [E_SOC]             @ 249,600,000  16,000,000
//   iRowPtr  i32 [N_NODE+1]          @ 265,600,000   1,200,004 (pad)
//   iCur     i32 [N_NODE]            @ 266,800,128   1,200,000
//   sRowPtr  i32 [N_USER+1]          @ 268,000,128     400,004 (pad)
//   sCur     i32 [N_USER]            @ 268,400,256     400,000
//   bSums    i32 [512]               @ 268,800,256       2,048
// total 268,802,304  (< 281.6 MB verified in prior session)
// inter f32 accumulator lives in d_out (76.8 MB, dead until final_kernel).
#define SOC_BYTES 12800000
#define FUSED_OFF 25600000
#define IPAIR_OFF 217600000
#define SPAIR_OFF 249600000
#define IRP_OFF   265600000
#define ICUR_OFF  266800128
#define SRP_OFF   268000128
#define SCUR_OFF  268400256
#define BSUM_OFF  268800256
#define WS_REQUIRED 268802304ull

#define SCAN_CHUNK 1024

// ---------------------------------------------------------------------------
__global__ __launch_bounds__(256) void fill_diag(float* __restrict__ o, int n,
                                                 float v) {
  int i = blockIdx.x * blockDim.x + threadIdx.x;
  if (i < n) o[i] = v;
}

__global__ __launch_bounds__(256) void zero_i32(int* __restrict__ p, int n) {
  int i = blockIdx.x * blockDim.x + threadIdx.x;
  if (i < n) p[i] = 0;
}

__global__ __launch_bounds__(256) void copy_i32(const int* __restrict__ s,
                                                int* __restrict__ d, int n) {
  int i = blockIdx.x * blockDim.x + threadIdx.x;
  if (i < n) d[i] = s[i];
}

// ---------------------------------------------------------------------------
// CSR build: histogram -> 3-pass exclusive scan -> scatter (val,col) pairs
// ---------------------------------------------------------------------------
__global__ __launch_bounds__(256) void hist_kernel(const int* __restrict__ rows,
                                                   int* cnt, int nE) {
  int e = blockIdx.x * blockDim.x + threadIdx.x;
  if (e < nE) atomicAdd(&cnt[rows[e]], 1);
}

// pass1: per-chunk sums
__global__ __launch_bounds__(256) void scan_pass1(const int* __restrict__ cnt,
                                                  int* __restrict__ bSums,
                                                  int n) {
  __shared__ int sred[4];
  int b = blockIdx.x, t = threadIdx.x;
  int base = b * SCAN_CHUNK;
  int s = 0;
  #pragma unroll
  for (int i = 0; i < 4; i++) {
    int idx = base + t + i * 256;
    if (idx < n) s += cnt[idx];
  }
  #pragma unroll
  for (int sh = 32; sh > 0; sh >>= 1) s += __shfl_xor(s, sh, 64);
  if ((t & 63) == 0) sred[t >> 6] = s;
  __syncthreads();
  if (t == 0) bSums[b] = sred[0] + sred[1] + sred[2] + sred[3];
}

// pass2: single block, exclusive scan of bSums[0..B) in place (B <= 512)
__global__ __launch_bounds__(512) void scan_pass2(int* bSums, int B) {
  __shared__ int waveTot[8];
  int t = threadIdx.x;
  int lane = t & 63, w = t >> 6;
  int orig = (t < B) ? bSums[t] : 0;
  int v = orig;
  #pragma unroll
  for (int sh = 1; sh < 64; sh <<= 1) {
    int u = __shfl_up(v, sh, 64);
    if (lane >= sh) v += u;
  }
  if (lane == 63) waveTot[w] = v;
  __syncthreads();
  int waveOff = 0;
  #pragma unroll
  for (int i = 0; i < 8; i++)
    if (i < w) waveOff += waveTot[i];
  v += waveOff;
  if (t < B) bSums[t] = v - orig;  // exclusive
}

// pass3: per-chunk exclusive scan + chunk offset -> rowPtr; rowPtr[n]=total
__global__ __launch_bounds__(256) void scan_pass3(const int* __restrict__ cnt,
                                                  const int* __restrict__ bSums,
                                                  int* __restrict__ rowPtr,
                                                  int n, int total) {
  __shared__ int waveTot[4];
  int b = blockIdx.x, t = threadIdx.x;
  int idx0 = b * SCAN_CHUNK + t * 4;
  int e0 = (idx0 + 0 < n) ? cnt[idx0 + 0] : 0;
  int e1 = (idx0 + 1 < n) ? cnt[idx0 + 1] : 0;
  int e2 = (idx0 + 2 < n) ? cnt[idx0 + 2] : 0;
  int e3 = (idx0 + 3 < n) ? cnt[idx0 + 3] : 0;
  int tsum = e0 + e1 + e2 + e3;
  int lane = t & 63, w = t >> 6;
  int v = tsum;
  #pragma unroll
  for (int sh = 1; sh < 64; sh <<= 1) {
    int u = __shfl_up(v, sh, 64);
    if (lane >= sh) v += u;
  }
  if (lane == 63) waveTot[w] = v;
  __syncthreads();
  int waveOff = 0;
  #pragma unroll
  for (int i = 0; i < 4; i++)
    if (i < w) waveOff += waveTot[i];
  int p0 = (v - tsum) + waveOff + bSums[b];
  int p1 = p0 + e0;
  int p2 = p1 + e1;
  int p3 = p2 + e2;
  if (idx0 + 0 < n) rowPtr[idx0 + 0] = p0;
  if (idx0 + 1 < n) rowPtr[idx0 + 1] = p1;
  if (idx0 + 2 < n) rowPtr[idx0 + 2] = p2;
  if (idx0 + 3 < n) rowPtr[idx0 + 3] = p3;
  if (b == 0 && t == 0) rowPtr[n] = total;
}

// scatter edges into CSR order as packed (valbits<<32 | col)
__global__ __launch_bounds__(256) void scatter_kernel(
    const int* __restrict__ rows, const int* __restrict__ cols,
    const float* __restrict__ vals, int* cursor,
    unsigned long long* __restrict__ pairs, int nE) {
  int e = blockIdx.x * blockDim.x + threadIdx.x;
  if (e >= nE) return;
  int r = rows[e];
  int p = atomicAdd(&cursor[r], 1);
  unsigned long long vb = (unsigned long long)__float_as_uint(vals[e]);
  pairs[p] = (vb << 32) | (unsigned int)cols[e];
}

// ---------------------------------------------------------------------------
// init: f32 inputs -> f32 inter buffer (ini, in d_out) and bf16 soc buffer
// ---------------------------------------------------------------------------
__global__ __launch_bounds__(256) void init_convert(
    const float* __restrict__ uE, const float* __restrict__ iE,
    float* __restrict__ inter, __hip_bfloat16* __restrict__ soc) {
  int idx = blockIdx.x * blockDim.x + threadIdx.x;
  if (idx >= NODE_ELEMS) return;
  if (idx < USER_ELEMS) {
    float v = uE[idx];
    soc[idx] = __float2bfloat16(v);
    inter[idx] = v;
  } else {
    inter[idx] = iE[idx - USER_ELEMS];
  }
}

// ---------------------------------------------------------------------------
// fuse: one wave per node row (unchanged from prior session)
// ---------------------------------------------------------------------------
__global__ __launch_bounds__(256) void fuse_kernel(
    const __hip_bfloat16* __restrict__ soc_cur,
    const float* __restrict__ inter_cur,
    const float* __restrict__ W_gate,   // (5,2,128)
    const float* __restrict__ b_gate,   // (5,2)
    int k, __hip_bfloat16* __restrict__ fused_k) {
  int g = blockIdx.x * blockDim.x + threadIdx.x;
  int row = g >> 6;
  int lane = g & 63;
  if (row >= N_NODE) return;
  int off = row * LATDIM + lane;

  if (row < N_USER) {
    float z = __bfloat162float(soc_cur[off]);
    float h = inter_cur[off];
    const float* wg = W_gate + k * 256;
    float p0 = z * wg[lane] + h * wg[64 + lane];
    float p1 = z * wg[128 + lane] + h * wg[192 + lane];
    #pragma unroll
    for (int s = 32; s > 0; s >>= 1) {
      p0 += __shfl_xor(p0, s, 64);
      p1 += __shfl_xor(p1, s, 64);
    }
    p0 += b_gate[k * 2 + 0];
    p1 += b_gate[k * 2 + 1];
    p0 = p0 >= 0.f ? p0 : 0.01f * p0;   // leaky_relu(0.01)
    p1 = p1 >= 0.f ? p1 : 0.01f * p1;
    float mx = fmaxf(p0, p1);
    float e0 = __expf(p0 - mx);
    float e1 = __expf(p1 - mx);
    float inv = 1.f / (e0 + e1);
    float o = z * (e0 * inv) + h * (e1 * inv);
    fused_k[off] = __float2bfloat16(o);
  } else {
    fused_k[off] = __float2bfloat16(inter_cur[off]);
  }
}

// ---------------------------------------------------------------------------
// pull-based SpMM: one wave per output row, lane = feature dim.
// Sequential f32 register accumulation; single non-atomic write.
// ---------------------------------------------------------------------------
__global__ __launch_bounds__(256) void spmm_pull_f32(
    const int* __restrict__ rowPtr,
    const unsigned long long* __restrict__ pairs,
    const __hip_bfloat16* __restrict__ x, float* __restrict__ out, int nRows) {
  int g = blockIdx.x * blockDim.x + threadIdx.x;
  int row = __builtin_amdgcn_readfirstlane(g >> 6);
  int lane = g & 63;
  if (row >= nRows) return;
  int start = rowPtr[row];
  int end = rowPtr[row + 1];
  float acc = 0.f;
  int e = start;
  for (; e + 1 < end; e += 2) {
    unsigned long long pk0 = pairs[e];
    unsigned long long pk1 = pairs[e + 1];
    int c0 = (int)(unsigned int)(pk0 & 0xffffffffu);
    int c1 = (int)(unsigned int)(pk1 & 0xffffffffu);
    float x0 = __bfloat162float(x[c0 * LATDIM + lane]);
    float x1 = __bfloat162float(x[c1 * LATDIM + lane]);
    acc += __uint_as_float((unsigned int)(pk0 >> 32)) * x0;
    acc += __uint_as_float((unsigned int)(pk1 >> 32)) * x1;
  }
  if (e < end) {
    unsigned long long pk = pairs[e];
    int c = (int)(unsigned int)(pk & 0xffffffffu);
    acc += __uint_as_float((unsigned int)(pk >> 32)) *
           __bfloat162float(x[c * LATDIM + lane]);
  }
  out[row * LATDIM + lane] = acc;
}

__global__ __launch_bounds__(256) void spmm_pull_bf16(
    const int* __restrict__ rowPtr,
    const unsigned long long* __restrict__ pairs,
    const __hip_bfloat16* __restrict__ x, __hip_bfloat16* __restrict__ out,
    int nRows) {
  int g = blockIdx.x * blockDim.x + threadIdx.x;
  int row = __builtin_amdgcn_readfirstlane(g >> 6);
  int lane = g & 63;
  if (row >= nRows) return;
  int start = rowPtr[row];
  int end = rowPtr[row + 1];
  float acc = 0.f;
  int e = start;
  for (; e + 1 < end; e += 2) {
    unsigned long long pk0 = pairs[e];
    unsigned long long pk1 = pairs[e + 1];
    int c0 = (int)(unsigned int)(pk0 & 0xffffffffu);
    int c1 = (int)(unsigned int)(pk1 & 0xffffffffu);
    float x0 = __bfloat162float(x[c0 * LATDIM + lane]);
    float x1 = __bfloat162float(x[c1 * LATDIM + lane]);
    acc += __uint_as_float((unsigned int)(pk0 >> 32)) * x0;
    acc += __uint_as_float((unsigned int)(pk1 >> 32)) * x1;
  }
  if (e < end) {
    unsigned long long pk = pairs[e];
    int c = (int)(unsigned int)(pk & 0xffffffffu);
    acc += __uint_as_float((unsigned int)(pk >> 32)) *
           __bfloat162float(x[c * LATDIM + lane]);
  }
  out[row * LATDIM + lane] = __float2bfloat16(acc);
}

// ---------------------------------------------------------------------------
// final: per-row 5-way attention over the 5 fused layers (unchanged)
// ---------------------------------------------------------------------------
__global__ __launch_bounds__(256) void final_kernel(
    const __hip_bfloat16* __restrict__ fused,
    const float* __restrict__ WL1,     // (5,320)
    const float* __restrict__ bL1,     // (5,)
    const float* __restrict__ WL2,
    const float* __restrict__ bL2,
    float* __restrict__ out) {
  int g = blockIdx.x * blockDim.x + threadIdx.x;
  int row = g >> 6;
  int lane = g & 63;
  if (row >= N_NODE) return;

  float f[5];
  #pragma unroll
  for (int k = 0; k < 5; k++)
    f[k] = __bfloat162float(fused[(size_t)k * NODE_ELEMS + row * LATDIM + lane]);

  const float* WL = (row < N_USER) ? WL1 : WL2;
  const float* bL = (row < N_USER) ? bL1 : bL2;

  float p[5];
  #pragma unroll
  for (int j = 0; j < 5; j++) {
    float s = 0.f;
    #pragma unroll
    for (int k = 0; k < 5; k++)
      s += f[k] * WL[j * 320 + k * 64 + lane];
    p[j] = s;
  }
  #pragma unroll
  for (int s = 32; s > 0; s >>= 1) {
    #pragma unroll
    for (int j = 0; j < 5; j++) p[j] += __shfl_xor(p[j], s, 64);
  }
  float mx = -1e30f;
  #pragma unroll
  for (int j = 0; j < 5; j++) {
    p[j] += bL[j];
    p[j] = p[j] >= 0.f ? p[j] : 0.01f * p[j];
    mx = fmaxf(mx, p[j]);
  }
  float sum = 0.f;
  #pragma unroll
  for (int j = 0; j < 5; j++) {
    p[j] = __expf(p[j] - mx);
    sum += p[j];
  }
  float inv = 1.f / sum;
  float o = 0.f;
  #pragma unroll
  for (int j = 0; j < 5; j++) o += (p[j] * inv) * f[j];
  out[row * LATDIM + lane] = o;
}

// ---------------------------------------------------------------------------
extern "C" void kernel_launch(void* const* d_in, const int* in_sizes, int n_in,
                              void* d_out, int out_size, void* d_ws,
                              size_t ws_size, hipStream_t stream) {
  const float* uE     = (const float*)d_in[0];
  const float* iE     = (const float*)d_in[1];
  const float* W_gate = (const float*)d_in[2];
  const float* b_gate = (const float*)d_in[3];
  const float* WL1    = (const float*)d_in[4];
  const float* bL1    = (const float*)d_in[5];
  const float* WL2    = (const float*)d_in[6];
  const float* bL2    = (const float*)d_in[7];
  const int* inter_rows = (const int*)d_in[8];
  const int* inter_cols = (const int*)d_in[9];
  const float* inter_vals = (const float*)d_in[10];
  const int* soc_rows   = (const int*)d_in[11];
  const int* soc_cols   = (const int*)d_in[12];
  const float* soc_vals = (const float*)d_in[13];
  float* out = (float*)d_out;

  if (ws_size < WS_REQUIRED) {
    float v = (float)(ws_size / (1024ull * 1024ull));
    fill_diag<<<(out_size + 255) / 256, 256, 0, stream>>>(out, out_size, v);
    return;
  }

  char* ws = (char*)d_ws;
  __hip_bfloat16* socBuf[2] = {(__hip_bfloat16*)ws,
                               (__hip_bfloat16*)(ws + SOC_BYTES)};
  __hip_bfloat16* fused = (__hip_bfloat16*)(ws + FUSED_OFF);
  unsigned long long* iPairs = (unsigned long long*)(ws + IPAIR_OFF);
  unsigned long long* sPairs = (unsigned long long*)(ws + SPAIR_OFF);
  int* iRowPtr = (int*)(ws + IRP_OFF);
  int* iCur    = (int*)(ws + ICUR_OFF);
  int* sRowPtr = (int*)(ws + SRP_OFF);
  int* sCur    = (int*)(ws + SCUR_OFF);
  int* bSums   = (int*)(ws + BSUM_OFF);
  float* interF32 = (float*)d_out;   // dead until final_kernel rewrites it

  // ---- CSR build: inter graph ----
  int iB = (N_NODE + SCAN_CHUNK - 1) / SCAN_CHUNK;   // 293
  zero_i32<<<(N_NODE + 255) / 256, 256, 0, stream>>>(iCur, N_NODE);
  hist_kernel<<<(E_INTER + 255) / 256, 256, 0, stream>>>(inter_rows, iCur,
                                                         E_INTER);
  scan_pass1<<<iB, 256, 0, stream>>>(iCur, bSums, N_NODE);
  scan_pass2<<<1, 512, 0, stream>>>(bSums, iB);
  scan_pass3<<<iB, 256, 0, stream>>>(iCur, bSums, iRowPtr, N_NODE, E_INTER);
  copy_i32<<<(N_NODE + 255) / 256, 256, 0, stream>>>(iRowPtr, iCur, N_NODE);
  scatter_kernel<<<(E_INTER + 255) / 256, 256, 0, stream>>>(
      inter_rows, inter_cols, inter_vals, iCur, iPairs, E_INTER);

  // ---- CSR build: soc graph ----
  int sB = (N_USER + SCAN_CHUNK - 1) / SCAN_CHUNK;   // 98
  zero_i32<<<(N_USER + 255) / 256, 256, 0, stream>>>(sCur, N_USER);
  hist_kernel<<<(E_SOC + 255) / 256, 256, 0, stream>>>(soc_rows, sCur, E_SOC);
  scan_pass1<<<sB, 256, 0, stream>>>(sCur, bSums, N_USER);
  scan_pass2<<<1, 512, 0, stream>>>(bSums, sB);
  scan_pass3<<<sB, 256, 0, stream>>>(sCur, bSums, sRowPtr, N_USER, E_SOC);
  copy_i32<<<(N_USER + 255) / 256, 256, 0, stream>>>(sRowPtr, sCur, N_USER);
  scatter_kernel<<<(E_SOC + 255) / 256, 256, 0, stream>>>(
      soc_rows, soc_cols, soc_vals, sCur, sPairs, E_SOC);

  // ---- main pipeline ----
  init_convert<<<NODE_ELEMS / 256, 256, 0, stream>>>(uE, iE, interF32,
                                                     socBuf[0]);

  for (int k = 0; k < 5; k++) {
    __hip_bfloat16* fk = fused + (size_t)k * NODE_ELEMS;
    fuse_kernel<<<NODE_ELEMS / 256, 256, 0, stream>>>(
        socBuf[k & 1], interF32, W_gate, b_gate, k, fk);
    if (k < 4) {
      spmm_pull_f32<<<NODE_ELEMS / 256, 256, 0, stream>>>(iRowPtr, iPairs, fk,
                                                          interF32, N_NODE);
      spmm_pull_bf16<<<USER_ELEMS / 256, 256, 0, stream>>>(
          sRowPtr, sPairs, socBuf[k & 1], socBuf[(k + 1) & 1], N_USER);
    }
  }

  final_kernel<<<NODE_ELEMS / 256, 256, 0, stream>>>(fused, WL1, bL1, WL2, bL2,
                                                     out);
}